// Round 2
// baseline (734.115 us; speedup 1.0000x reference)
//
#include <hip/hip_runtime.h>
#include <hip/hip_bf16.h>
#include <cstdint>
#include <cstddef>

#define T_DIM 2048
#define B_DIM 32
#define D_DIM 512
#define H_DIM 768
#define C_DIM 10
#define K_DIM D_DIM             /* 512  */
#define N_DIM (4 * H_DIM)       /* 3072 */

#define TC 256                  /* timesteps per chunk */
#define NCHUNK (T_DIM / TC)     /* 8 */
#define MC (TC * B_DIM)         /* 8192 rows per chunk GEMM */

typedef __attribute__((ext_vector_type(8))) short short8;
typedef __attribute__((ext_vector_type(4))) float float4v;

__device__ inline unsigned short f2bf(float f) {
  unsigned int u = __builtin_bit_cast(unsigned int, f);
  unsigned int r = (u + 0x7FFFu + ((u >> 16) & 1u)) >> 16;
  return (unsigned short)r;
}
__device__ inline float bf2f(unsigned short s) {
  unsigned int u = ((unsigned int)s) << 16;
  return __builtin_bit_cast(float, u);
}
__device__ inline float fast_rcp(float x) { return __builtin_amdgcn_rcpf(x); }
__device__ inline float fast_exp2(float x) { return __builtin_amdgcn_exp2f(x); }
__device__ inline float sigmoid_f(float x) {
  float e = fast_exp2(-1.4426950408889634f * x);
  return fast_rcp(1.0f + e);
}
__device__ inline float tanh_f(float x) {
  // tanh(x) = 1 - 2/(exp(2x)+1); |x| small here so no overflow concerns
  float e = fast_exp2(2.885390081777927f * x);
  return 1.0f - 2.0f * fast_rcp(e + 1.0f);
}

// ---------------------------------------------------------------------------
// Kernel 1: chunked embedding gather + fp32->bf16. x_c points at chunk rows.
// ---------------------------------------------------------------------------
__global__ __launch_bounds__(256) void gather_embed_kernel(
    const int* __restrict__ x_c, const float* __restrict__ table,
    unsigned short* __restrict__ ebfc) {
  int idx = blockIdx.x * 256 + threadIdx.x;           // MC*K/4 = 1,048,576
  int m = idx >> 7;                                    // 128 float4 per row
  int k4 = (idx & 127) << 2;
  int row = x_c[m];
  float4 v = *(const float4*)(table + (size_t)row * D_DIM + k4);
  ushort4 o;
  o.x = f2bf(v.x); o.y = f2bf(v.y); o.z = f2bf(v.z); o.w = f2bf(v.w);
  *(ushort4*)(ebfc + (size_t)m * D_DIM + k4) = o;
}

// ---------------------------------------------------------------------------
// Kernel 2: concat 4 weight matrices -> bf16  wcat[n][k], n: [Wx;Wf;Wr;Wcx]
// ---------------------------------------------------------------------------
__global__ __launch_bounds__(256) void convert_w_kernel(
    const float* __restrict__ Wx, const float* __restrict__ Wf,
    const float* __restrict__ Wr, const float* __restrict__ Wcx,
    unsigned short* __restrict__ wcat) {
  int idx = blockIdx.x * 256 + threadIdx.x;           // 393,216 total
  int n = idx >> 7;
  int k4 = (idx & 127) << 2;
  int mat = n / H_DIM;
  int h = n - mat * H_DIM;
  const float* src = (mat == 0) ? Wx : (mat == 1) ? Wf : (mat == 2) ? Wr : Wcx;
  float4 v = *(const float4*)(src + (size_t)h * D_DIM + k4);
  ushort4 o;
  o.x = f2bf(v.x); o.y = f2bf(v.y); o.z = f2bf(v.z); o.w = f2bf(v.w);
  *(ushort4*)(wcat + (size_t)n * D_DIM + k4) = o;
}

// ---------------------------------------------------------------------------
// Kernel 3: bf16 MFMA GEMM for one chunk.
// C[m][n] = sum_k ebfc[m][k]*wcat[n][k],  m in [0,MC), n in [0,3072)
// 128x128 tile, 4 waves, 4x4 x mfma_f32_16x16x32_bf16 per wave.
// Fused epilogue: mat0 xp, mat1 sigmoid(+b_f), mat2 sigmoid(+b_r), mat3 +b_cx
// projc layout: [mat][t*B+b][h] bf16 (t local to chunk)
// ---------------------------------------------------------------------------
#define BM 128
#define BN 128
#define BK 32
#define LDK 40  /* +8 bf16 pad: 80B row stride breaks bank conflicts */

__global__ __launch_bounds__(256) void gemm_kernel(
    const unsigned short* __restrict__ ebfc,
    const unsigned short* __restrict__ wcat,
    const float* __restrict__ b_f, const float* __restrict__ b_r,
    const float* __restrict__ b_cx,
    unsigned short* __restrict__ projc) {
  __shared__ __align__(16) unsigned short As[BM * LDK];
  __shared__ __align__(16) unsigned short Bs[BN * LDK];

  int tid  = threadIdx.x;
  int wave = tid >> 6;
  int lane = tid & 63;
  int quad = lane >> 4;
  int l16  = lane & 15;
  int m0 = blockIdx.y * BM;
  int n0 = blockIdx.x * BN;
  int wm = (wave >> 1) * 64;
  int wn = (wave & 1) * 64;

  float4v acc[4][4] = {};

  for (int kt = 0; kt < K_DIM; kt += BK) {
    __syncthreads();
#pragma unroll
    for (int v = 0; v < 2; v++) {
      int idx = v * 256 + tid;          // 512 chunks of 8 bf16
      int row = idx >> 2;               // 4 chunks per row of 32
      int kc  = (idx & 3) << 3;
      short8 a = *(const short8*)(ebfc + (size_t)(m0 + row) * K_DIM + kt + kc);
      short8 b = *(const short8*)(wcat + (size_t)(n0 + row) * K_DIM + kt + kc);
      *(short8*)(As + row * LDK + kc) = a;
      *(short8*)(Bs + row * LDK + kc) = b;
    }
    __syncthreads();
    short8 af[4], bfr[4];
#pragma unroll
    for (int i = 0; i < 4; i++)
      af[i] = *(const short8*)(As + (wm + i * 16 + l16) * LDK + quad * 8);
#pragma unroll
    for (int j = 0; j < 4; j++)
      bfr[j] = *(const short8*)(Bs + (wn + j * 16 + l16) * LDK + quad * 8);
#pragma unroll
    for (int i = 0; i < 4; i++)
#pragma unroll
      for (int j = 0; j < 4; j++)
        acc[i][j] = __builtin_amdgcn_mfma_f32_16x16x32_bf16(af[i], bfr[j], acc[i][j], 0, 0, 0);
  }

  // epilogue: mat is uniform per block (H=768 = 6*BN)
  int mat = n0 / H_DIM;
  const float* bias = (mat == 1) ? b_f : (mat == 2) ? b_r : b_cx;
  size_t matBase = (size_t)mat * MC * H_DIM;
#pragma unroll
  for (int i = 0; i < 4; i++) {
    int mrow = m0 + wm + i * 16 + quad * 4;
#pragma unroll
    for (int j = 0; j < 4; j++) {
      int n = n0 + wn + j * 16 + l16;
      int h = n - mat * H_DIM;
      float bv = (mat == 0) ? 0.0f : bias[h];
#pragma unroll
      for (int r = 0; r < 4; r++) {
        float v = acc[i][j][r] + bv;
        if (mat == 1 || mat == 2) v = sigmoid_f(v);
        projc[matBase + (size_t)(mrow + r) * H_DIM + h] = f2bf(v);
      }
    }
  }
}

// ---------------------------------------------------------------------------
// Kernel 4: SRU recurrence + tanh-max-pool over one chunk (TC steps).
// thread owns (b,h); 96 blocks x 256 threads. LDS double-buffered staging of
// TS=8 timesteps x 4 arrays, 16B global loads. State carried in c_state/hm_state.
// On last chunk: pooled[b][h] = tanh(tanh(max_t h_t))
// ---------------------------------------------------------------------------
#define TS 8
__global__ __launch_bounds__(256) void recurrence_kernel(
    const unsigned short* __restrict__ projc,
    float* __restrict__ c_state, float* __restrict__ hm_state,
    float* __restrict__ pooled, int first, int last) {
  __shared__ __align__(16) unsigned short buf[2][4][TS][256];
  int tid = threadIdx.x;
  int b  = blockIdx.x / 3;
  int hc = blockIdx.x % 3;
  int tt = tid >> 5;              // 0..7 (timestep within stage)
  int hh = (tid & 31) << 3;       // 0..248 step 8 (h-chunk of 8)

  const size_t matStride = (size_t)MC * H_DIM;
  size_t base = (size_t)b * H_DIM + hc * 256 + hh;
  int gid = b * H_DIM + hc * 256 + tid;

  short8 regs[4];
#pragma unroll
  for (int a = 0; a < 4; a++)
    regs[a] = *(const short8*)(projc + a * matStride + (size_t)tt * B_DIM * H_DIM + base);
#pragma unroll
  for (int a = 0; a < 4; a++)
    *(short8*)(&buf[0][a][tt][hh]) = regs[a];
  __syncthreads();

  float c, hm;
  if (first) { c = 0.0f; hm = -1e30f; }
  else       { c = c_state[gid]; hm = hm_state[gid]; }

  const int NCH = TC / TS;        // 32 stages per chunk
  for (int ch = 0; ch < NCH; ch++) {
    bool more = (ch + 1) < NCH;
    if (more) {
      int t0 = (ch + 1) * TS;
#pragma unroll
      for (int a = 0; a < 4; a++)
        regs[a] = *(const short8*)(projc + a * matStride + (size_t)(t0 + tt) * B_DIM * H_DIM + base);
    }
    int cur = ch & 1;
#pragma unroll
    for (int t = 0; t < TS; t++) {
      float xp = bf2f(buf[cur][0][t][tid]);
      float f  = bf2f(buf[cur][1][t][tid]);
      float r  = bf2f(buf[cur][2][t][tid]);
      float cx = bf2f(buf[cur][3][t][tid]);
      c = fmaf(f, c - xp, xp);          // f*c + (1-f)*xp
      float th = tanh_f(c);
      float h  = fmaf(r, th - cx, cx);  // r*tanh(c) + (1-r)*cx
      hm = fmaxf(hm, h);
    }
    if (more) {
      int nxt = (ch + 1) & 1;
#pragma unroll
      for (int a = 0; a < 4; a++)
        *(short8*)(&buf[nxt][a][tt][hh]) = regs[a];
    }
    __syncthreads();
  }

  c_state[gid]  = c;
  hm_state[gid] = hm;
  if (last) pooled[gid] = tanh_f(tanh_f(hm));
}

// ---------------------------------------------------------------------------
// Kernel 5: classifier  logit[b][c] = pooled[b]·W_out[c] + b_out[c]
// one wave per (b,c)
// ---------------------------------------------------------------------------
__global__ __launch_bounds__(64) void classifier_kernel(
    const float* __restrict__ pooled, const float* __restrict__ W_out,
    const float* __restrict__ b_out, float* __restrict__ out) {
  int b = blockIdx.x / C_DIM;
  int c = blockIdx.x % C_DIM;
  int lane = threadIdx.x;
  float s = 0.0f;
#pragma unroll
  for (int i = 0; i < H_DIM / 64; i++) {
    int h = i * 64 + lane;
    s += pooled[(size_t)b * H_DIM + h] * W_out[(size_t)c * H_DIM + h];
  }
#pragma unroll
  for (int off = 32; off; off >>= 1) s += __shfl_down(s, off, 64);
  if (lane == 0) out[b * C_DIM + c] = s + b_out[c];
}

// ---------------------------------------------------------------------------
extern "C" void kernel_launch(void* const* d_in, const int* in_sizes, int n_in,
                              void* d_out, int out_size, void* d_ws, size_t ws_size,
                              hipStream_t stream) {
  const int*   x     = (const int*)d_in[0];
  const float* table = (const float*)d_in[1];
  const float* W_x   = (const float*)d_in[2];
  const float* W_f   = (const float*)d_in[3];
  const float* b_f   = (const float*)d_in[4];
  const float* W_r   = (const float*)d_in[5];
  const float* b_r   = (const float*)d_in[6];
  const float* W_cx  = (const float*)d_in[7];
  const float* b_cx  = (const float*)d_in[8];
  const float* W_out = (const float*)d_in[9];
  const float* b_out = (const float*)d_in[10];

  // workspace layout (~59.3 MB total)
  char* ws = (char*)d_ws;
  const size_t WCAT_B  = (size_t)N_DIM * K_DIM * 2;        //  3,145,728
  const size_t EBFC_B  = (size_t)MC * K_DIM * 2;           //  8,388,608
  const size_t PROJC_B = (size_t)4 * MC * H_DIM * 2;       // 50,331,648
  const size_t ST_B    = (size_t)B_DIM * H_DIM * 4;        //     98,304
  unsigned short* wcat   = (unsigned short*)ws;
  unsigned short* ebfc   = (unsigned short*)(ws + WCAT_B);
  unsigned short* projc  = (unsigned short*)(ws + WCAT_B + EBFC_B);
  float*          c_st   = (float*)(ws + WCAT_B + EBFC_B + PROJC_B);
  float*          hm_st  = (float*)(ws + WCAT_B + EBFC_B + PROJC_B + ST_B);
  float*          pooled = (float*)(ws + WCAT_B + EBFC_B + PROJC_B + 2 * ST_B);

  convert_w_kernel<<<(N_DIM * K_DIM / 4) / 256, 256, 0, stream>>>(W_x, W_f, W_r, W_cx, wcat);

  dim3 g(N_DIM / BN, MC / BM);   // (24, 64)
  for (int ch = 0; ch < NCHUNK; ch++) {
    gather_embed_kernel<<<(MC * K_DIM / 4) / 256, 256, 0, stream>>>(x + (size_t)ch * MC, table, ebfc);
    gemm_kernel<<<g, 256, 0, stream>>>(ebfc, wcat, b_f, b_r, b_cx, projc);
    recurrence_kernel<<<B_DIM * 3, 256, 0, stream>>>(projc, c_st, hm_st, pooled,
                                                     ch == 0, ch == NCHUNK - 1);
  }
  classifier_kernel<<<B_DIM * C_DIM, 64, 0, stream>>>(pooled, W_out, b_out, (float*)d_out);
}

// Round 3
// 635.252 us; speedup vs baseline: 1.1556x; 1.1556x over previous
//
#include <hip/hip_runtime.h>
#include <hip/hip_bf16.h>
#include <cstdint>
#include <cstddef>

#define T_DIM 2048
#define B_DIM 32
#define D_DIM 512
#define H_DIM 768
#define C_DIM 10
#define K_DIM D_DIM             /* 512  */
#define N_DIM (4 * H_DIM)       /* 3072 */

#define TC 512                  /* timesteps per chunk */
#define NCHUNK (T_DIM / TC)     /* 4 */
#define MC (TC * B_DIM)         /* 16384 rows per chunk GEMM */

typedef __attribute__((ext_vector_type(8))) short short8;
typedef __attribute__((ext_vector_type(4))) float float4v;

__device__ inline unsigned short f2bf(float f) {
  unsigned int u = __builtin_bit_cast(unsigned int, f);
  unsigned int r = (u + 0x7FFFu + ((u >> 16) & 1u)) >> 16;
  return (unsigned short)r;
}
__device__ inline float bf2f(unsigned short s) {
  unsigned int u = ((unsigned int)s) << 16;
  return __builtin_bit_cast(float, u);
}
__device__ inline float fast_rcp(float x) { return __builtin_amdgcn_rcpf(x); }
__device__ inline float fast_exp2(float x) { return __builtin_amdgcn_exp2f(x); }
__device__ inline float sigmoid_f(float x) {
  float e = fast_exp2(-1.4426950408889634f * x);
  return fast_rcp(1.0f + e);
}
__device__ inline float tanh_f(float x) {
  // tanh(x) = 1 - 2/(exp(2x)+1); |x| small here so no overflow concerns
  float e = fast_exp2(2.885390081777927f * x);
  return 1.0f - 2.0f * fast_rcp(e + 1.0f);
}

// ---------------------------------------------------------------------------
// Kernel 1: chunked embedding gather + fp32->bf16. x_c points at chunk rows.
// ---------------------------------------------------------------------------
__global__ __launch_bounds__(256) void gather_embed_kernel(
    const int* __restrict__ x_c, const float* __restrict__ table,
    unsigned short* __restrict__ ebfc) {
  int idx = blockIdx.x * 256 + threadIdx.x;           // MC*K/4 = 2,097,152
  int m = idx >> 7;                                    // 128 float4 per row
  int k4 = (idx & 127) << 2;
  int row = x_c[m];
  float4 v = *(const float4*)(table + (size_t)row * D_DIM + k4);
  ushort4 o;
  o.x = f2bf(v.x); o.y = f2bf(v.y); o.z = f2bf(v.z); o.w = f2bf(v.w);
  *(ushort4*)(ebfc + (size_t)m * D_DIM + k4) = o;
}

// ---------------------------------------------------------------------------
// Kernel 2: concat 4 weight matrices -> bf16  wcat[n][k], n: [Wx;Wf;Wr;Wcx]
// ---------------------------------------------------------------------------
__global__ __launch_bounds__(256) void convert_w_kernel(
    const float* __restrict__ Wx, const float* __restrict__ Wf,
    const float* __restrict__ Wr, const float* __restrict__ Wcx,
    unsigned short* __restrict__ wcat) {
  int idx = blockIdx.x * 256 + threadIdx.x;           // 393,216 total
  int n = idx >> 7;
  int k4 = (idx & 127) << 2;
  int mat = n / H_DIM;
  int h = n - mat * H_DIM;
  const float* src = (mat == 0) ? Wx : (mat == 1) ? Wf : (mat == 2) ? Wr : Wcx;
  float4 v = *(const float4*)(src + (size_t)h * D_DIM + k4);
  ushort4 o;
  o.x = f2bf(v.x); o.y = f2bf(v.y); o.z = f2bf(v.z); o.w = f2bf(v.w);
  *(ushort4*)(wcat + (size_t)n * D_DIM + k4) = o;
}

// ---------------------------------------------------------------------------
// Kernel 3: bf16 MFMA GEMM for one chunk (m97 structure).
// C[m][n] = sum_k ebfc[m][k]*wcat[n][k],  m in [0,MC), n in [0,3072)
// 128x128 tile, 4 waves, 4x4 x mfma_f32_16x16x32_bf16 per wave.
// Staging via global_load_lds width=16 (wave-uniform base + lane*16 -> LDS
// must be unpadded); bank conflicts broken by XOR swizzle on the 16B chunk:
//   physical chunk p holds logical chunk p ^ ((row>>1)&3)
// ds_read_b128 then hits each bank with <=2 lanes (free per m136).
// Fused epilogue: mat0 xp, mat1 sigmoid(+b_f), mat2 sigmoid(+b_r), mat3 +b_cx
// projc layout: [mat][t*B+b][h] bf16 (t local to chunk)
// ---------------------------------------------------------------------------
#define BM 128
#define BN 128
#define BK 32

__global__ __launch_bounds__(256) void gemm_kernel(
    const unsigned short* __restrict__ ebfc,
    const unsigned short* __restrict__ wcat,
    const float* __restrict__ b_f, const float* __restrict__ b_r,
    const float* __restrict__ b_cx,
    unsigned short* __restrict__ projc) {
  __shared__ __align__(16) unsigned short As[BM * BK];
  __shared__ __align__(16) unsigned short Bs[BN * BK];

  int tid  = threadIdx.x;
  int wave = tid >> 6;
  int lane = tid & 63;
  int quad = lane >> 4;
  int l16  = lane & 15;
  int m0 = blockIdx.y * BM;
  int n0 = blockIdx.x * BN;
  int wm = (wave >> 1) * 64;
  int wn = (wave & 1) * 64;

  // Precompute staging source offsets (swizzled logical chunk).
  // idx = v*256 + tid ; row = idx>>2 ; physical chunk = idx&3
  int row0 = tid >> 2;
  int cp0  = tid & 3;
  int cl0  = cp0 ^ ((row0 >> 1) & 3);
  int row1 = (256 + tid) >> 2;
  int cp1  = tid & 3;
  int cl1  = cp1 ^ ((row1 >> 1) & 3);

  float4v acc[4][4] = {};

  for (int kt = 0; kt < K_DIM; kt += BK) {
    __syncthreads();
    {
      const unsigned short* ga0 = ebfc + (size_t)(m0 + row0) * K_DIM + kt + cl0 * 8;
      const unsigned short* gb0 = wcat + (size_t)(n0 + row0) * K_DIM + kt + cl0 * 8;
      const unsigned short* ga1 = ebfc + (size_t)(m0 + row1) * K_DIM + kt + cl1 * 8;
      const unsigned short* gb1 = wcat + (size_t)(n0 + row1) * K_DIM + kt + cl1 * 8;
      __builtin_amdgcn_global_load_lds(
          (const __attribute__((address_space(1))) void*)ga0,
          (__attribute__((address_space(3))) void*)(As + tid * 8), 16, 0, 0);
      __builtin_amdgcn_global_load_lds(
          (const __attribute__((address_space(1))) void*)gb0,
          (__attribute__((address_space(3))) void*)(Bs + tid * 8), 16, 0, 0);
      __builtin_amdgcn_global_load_lds(
          (const __attribute__((address_space(1))) void*)ga1,
          (__attribute__((address_space(3))) void*)(As + (256 + tid) * 8), 16, 0, 0);
      __builtin_amdgcn_global_load_lds(
          (const __attribute__((address_space(1))) void*)gb1,
          (__attribute__((address_space(3))) void*)(Bs + (256 + tid) * 8), 16, 0, 0);
    }
    __syncthreads();
    short8 af[4], bfr[4];
#pragma unroll
    for (int i = 0; i < 4; i++) {
      int r = wm + i * 16 + l16;
      int p = quad ^ ((r >> 1) & 3);
      af[i] = *(const short8*)(As + r * BK + p * 8);
    }
#pragma unroll
    for (int j = 0; j < 4; j++) {
      int r = wn + j * 16 + l16;
      int p = quad ^ ((r >> 1) & 3);
      bfr[j] = *(const short8*)(Bs + r * BK + p * 8);
    }
#pragma unroll
    for (int i = 0; i < 4; i++)
#pragma unroll
      for (int j = 0; j < 4; j++)
        acc[i][j] = __builtin_amdgcn_mfma_f32_16x16x32_bf16(af[i], bfr[j], acc[i][j], 0, 0, 0);
  }

  // epilogue: mat is uniform per block (H=768 = 6*BN)
  int mat = n0 / H_DIM;
  const float* bias = (mat == 1) ? b_f : (mat == 2) ? b_r : b_cx;
  size_t matBase = (size_t)mat * MC * H_DIM;
#pragma unroll
  for (int i = 0; i < 4; i++) {
    int mrow = m0 + wm + i * 16 + quad * 4;
#pragma unroll
    for (int j = 0; j < 4; j++) {
      int n = n0 + wn + j * 16 + l16;
      int h = n - mat * H_DIM;
      float bv = (mat == 0) ? 0.0f : bias[h];
#pragma unroll
      for (int r = 0; r < 4; r++) {
        float v = acc[i][j][r] + bv;
        if (mat == 1 || mat == 2) v = sigmoid_f(v);
        projc[matBase + (size_t)(mrow + r) * H_DIM + h] = f2bf(v);
      }
    }
  }
}

// ---------------------------------------------------------------------------
// Kernel 4: SRU recurrence + tanh-max-pool over one chunk (TC steps).
// 192 blocks x 128 threads: block = (b, hc) with hc in [0,6), 128 h each.
// Thread owns (b,h). LDS double-buffered staging of TS=8 timesteps x 4
// arrays, 16B global loads. State carried in c_state/hm_state.
// On last chunk: pooled[b][h] = tanh(tanh(max_t h_t))
// ---------------------------------------------------------------------------
#define TS 8
__global__ __launch_bounds__(128) void recurrence_kernel(
    const unsigned short* __restrict__ projc,
    float* __restrict__ c_state, float* __restrict__ hm_state,
    float* __restrict__ pooled, int first, int last) {
  __shared__ __align__(16) unsigned short buf[2][4][TS][128];
  int tid = threadIdx.x;
  int b  = blockIdx.x / 6;
  int hc = blockIdx.x % 6;
  int tt = tid >> 4;              // 0..7 (timestep within stage)
  int hh = (tid & 15) << 3;       // 0..120 step 8 (h-chunk of 8)

  const size_t matStride = (size_t)MC * H_DIM;
  size_t base = (size_t)b * H_DIM + hc * 128 + hh;
  int gid = b * H_DIM + hc * 128 + tid;

  short8 regs[4];
#pragma unroll
  for (int a = 0; a < 4; a++)
    regs[a] = *(const short8*)(projc + a * matStride + (size_t)tt * B_DIM * H_DIM + base);
#pragma unroll
  for (int a = 0; a < 4; a++)
    *(short8*)(&buf[0][a][tt][hh]) = regs[a];
  __syncthreads();

  float c, hm;
  if (first) { c = 0.0f; hm = -1e30f; }
  else       { c = c_state[gid]; hm = hm_state[gid]; }

  const int NCH = TC / TS;        // 64 stages per chunk
  for (int ch = 0; ch < NCH; ch++) {
    bool more = (ch + 1) < NCH;
    if (more) {
      int t0 = (ch + 1) * TS;
#pragma unroll
      for (int a = 0; a < 4; a++)
        regs[a] = *(const short8*)(projc + a * matStride + (size_t)(t0 + tt) * B_DIM * H_DIM + base);
    }
    int cur = ch & 1;
#pragma unroll
    for (int t = 0; t < TS; t++) {
      float xp = bf2f(buf[cur][0][t][tid]);
      float f  = bf2f(buf[cur][1][t][tid]);
      float r  = bf2f(buf[cur][2][t][tid]);
      float cx = bf2f(buf[cur][3][t][tid]);
      c = fmaf(f, c - xp, xp);          // f*c + (1-f)*xp
      float th = tanh_f(c);
      float h  = fmaf(r, th - cx, cx);  // r*tanh(c) + (1-r)*cx
      hm = fmaxf(hm, h);
    }
    if (more) {
      int nxt = (ch + 1) & 1;
#pragma unroll
      for (int a = 0; a < 4; a++)
        *(short8*)(&buf[nxt][a][tt][hh]) = regs[a];
    }
    __syncthreads();
  }

  c_state[gid]  = c;
  hm_state[gid] = hm;
  if (last) pooled[gid] = tanh_f(tanh_f(hm));
}

// ---------------------------------------------------------------------------
// Kernel 5: classifier  logit[b][c] = pooled[b]·W_out[c] + b_out[c]
// one wave per (b,c)
// ---------------------------------------------------------------------------
__global__ __launch_bounds__(64) void classifier_kernel(
    const float* __restrict__ pooled, const float* __restrict__ W_out,
    const float* __restrict__ b_out, float* __restrict__ out) {
  int b = blockIdx.x / C_DIM;
  int c = blockIdx.x % C_DIM;
  int lane = threadIdx.x;
  float s = 0.0f;
#pragma unroll
  for (int i = 0; i < H_DIM / 64; i++) {
    int h = i * 64 + lane;
    s += pooled[(size_t)b * H_DIM + h] * W_out[(size_t)c * H_DIM + h];
  }
#pragma unroll
  for (int off = 32; off; off >>= 1) s += __shfl_down(s, off, 64);
  if (lane == 0) out[b * C_DIM + c] = s + b_out[c];
}

// ---------------------------------------------------------------------------
extern "C" void kernel_launch(void* const* d_in, const int* in_sizes, int n_in,
                              void* d_out, int out_size, void* d_ws, size_t ws_size,
                              hipStream_t stream) {
  const int*   x     = (const int*)d_in[0];
  const float* table = (const float*)d_in[1];
  const float* W_x   = (const float*)d_in[2];
  const float* W_f   = (const float*)d_in[3];
  const float* b_f   = (const float*)d_in[4];
  const float* W_r   = (const float*)d_in[5];
  const float* b_r   = (const float*)d_in[6];
  const float* W_cx  = (const float*)d_in[7];
  const float* b_cx  = (const float*)d_in[8];
  const float* W_out = (const float*)d_in[9];
  const float* b_out = (const float*)d_in[10];

  // workspace layout (~121 MB total; ws_size ~411 MB per harness fill size)
  char* ws = (char*)d_ws;
  const size_t WCAT_B  = (size_t)N_DIM * K_DIM * 2;        //   3,145,728
  const size_t EBFC_B  = (size_t)MC * K_DIM * 2;           //  16,777,216
  const size_t PROJC_B = (size_t)4 * MC * H_DIM * 2;       // 100,663,296
  const size_t ST_B    = (size_t)B_DIM * H_DIM * 4;        //      98,304
  unsigned short* wcat   = (unsigned short*)ws;
  unsigned short* ebfc   = (unsigned short*)(ws + WCAT_B);
  unsigned short* projc  = (unsigned short*)(ws + WCAT_B + EBFC_B);
  float*          c_st   = (float*)(ws + WCAT_B + EBFC_B + PROJC_B);
  float*          hm_st  = (float*)(ws + WCAT_B + EBFC_B + PROJC_B + ST_B);
  float*          pooled = (float*)(ws + WCAT_B + EBFC_B + PROJC_B + 2 * ST_B);

  convert_w_kernel<<<(N_DIM * K_DIM / 4) / 256, 256, 0, stream>>>(W_x, W_f, W_r, W_cx, wcat);

  dim3 g(N_DIM / BN, MC / BM);   // (24, 128)
  for (int ch = 0; ch < NCHUNK; ch++) {
    gather_embed_kernel<<<(MC * K_DIM / 4) / 256, 256, 0, stream>>>(x + (size_t)ch * MC, table, ebfc);
    gemm_kernel<<<g, 256, 0, stream>>>(ebfc, wcat, b_f, b_r, b_cx, projc);
    recurrence_kernel<<<B_DIM * 6, 128, 0, stream>>>(projc, c_st, hm_st, pooled,
                                                     ch == 0, ch == NCHUNK - 1);
  }
  classifier_kernel<<<B_DIM * C_DIM, 64, 0, stream>>>(pooled, W_out, b_out, (float*)d_out);
}

// Round 4
// 604.110 us; speedup vs baseline: 1.2152x; 1.0516x over previous
//
#include <hip/hip_runtime.h>
#include <hip/hip_bf16.h>
#include <cstdint>
#include <cstddef>

#define T_DIM 2048
#define B_DIM 32
#define D_DIM 512
#define H_DIM 768
#define C_DIM 10
#define K_DIM D_DIM             /* 512  */
#define N_DIM (4 * H_DIM)       /* 3072 */

#define TC 1024                 /* timesteps per chunk */
#define NCHUNK (T_DIM / TC)     /* 2 */
#define MC (TC * B_DIM)         /* 32768 rows per chunk GEMM */

#define L_SEG 64                /* scan segment length */
#define S_SEG (TC / L_SEG)      /* 16 segments per chunk */
#define BH (B_DIM * H_DIM)      /* 24576 chains */

typedef __attribute__((ext_vector_type(8))) short short8;
typedef __attribute__((ext_vector_type(4))) float float4v;

__device__ inline unsigned short f2bf(float f) {
  unsigned int u = __builtin_bit_cast(unsigned int, f);
  unsigned int r = (u + 0x7FFFu + ((u >> 16) & 1u)) >> 16;
  return (unsigned short)r;
}
__device__ inline float bf2f(unsigned short s) {
  unsigned int u = ((unsigned int)s) << 16;
  return __builtin_bit_cast(float, u);
}
__device__ inline float fast_rcp(float x) { return __builtin_amdgcn_rcpf(x); }
__device__ inline float fast_exp2(float x) { return __builtin_amdgcn_exp2f(x); }
__device__ inline float sigmoid_f(float x) {
  float e = fast_exp2(-1.4426950408889634f * x);
  return fast_rcp(1.0f + e);
}
__device__ inline float tanh_f(float x) {
  float e = fast_exp2(2.885390081777927f * x);
  return 1.0f - 2.0f * fast_rcp(e + 1.0f);
}
__device__ inline void gld16(const unsigned short* g, unsigned short* l) {
  __builtin_amdgcn_global_load_lds(
      (const __attribute__((address_space(1))) void*)g,
      (__attribute__((address_space(3))) void*)l, 16, 0, 0);
}

// ---------------------------------------------------------------------------
// Kernel 1: chunked embedding gather + fp32->bf16
// ---------------------------------------------------------------------------
__global__ __launch_bounds__(256) void gather_embed_kernel(
    const int* __restrict__ x_c, const float* __restrict__ table,
    unsigned short* __restrict__ ebfc) {
  int idx = blockIdx.x * 256 + threadIdx.x;
  int m = idx >> 7;
  int k4 = (idx & 127) << 2;
  int row = x_c[m];
  float4 v = *(const float4*)(table + (size_t)row * D_DIM + k4);
  ushort4 o;
  o.x = f2bf(v.x); o.y = f2bf(v.y); o.z = f2bf(v.z); o.w = f2bf(v.w);
  *(ushort4*)(ebfc + (size_t)m * D_DIM + k4) = o;
}

// ---------------------------------------------------------------------------
// Kernel 2: concat 4 weight matrices -> bf16  wcat[n][k], n: [Wx;Wf;Wr;Wcx]
// ---------------------------------------------------------------------------
__global__ __launch_bounds__(256) void convert_w_kernel(
    const float* __restrict__ Wx, const float* __restrict__ Wf,
    const float* __restrict__ Wr, const float* __restrict__ Wcx,
    unsigned short* __restrict__ wcat) {
  int idx = blockIdx.x * 256 + threadIdx.x;
  int n = idx >> 7;
  int k4 = (idx & 127) << 2;
  int mat = n / H_DIM;
  int h = n - mat * H_DIM;
  const float* src = (mat == 0) ? Wx : (mat == 1) ? Wf : (mat == 2) ? Wr : Wcx;
  float4 v = *(const float4*)(src + (size_t)h * D_DIM + k4);
  ushort4 o;
  o.x = f2bf(v.x); o.y = f2bf(v.y); o.z = f2bf(v.z); o.w = f2bf(v.w);
  *(ushort4*)(wcat + (size_t)n * D_DIM + k4) = o;
}

// ---------------------------------------------------------------------------
// Kernel 3: bf16 MFMA GEMM, explicit LDS double-buffer (1 barrier/iter).
// 128x128 tile, BK=32, global_load_lds w=16, XOR-swizzled chunks.
// Epilogue: bias/sigmoid fused, LDS transpose (136-stride pad) -> dwordx4.
// ---------------------------------------------------------------------------
#define BM 128
#define BN 128
#define BK 32

__global__ __launch_bounds__(256) void gemm_kernel(
    const unsigned short* __restrict__ ebfc,
    const unsigned short* __restrict__ wcat,
    const float* __restrict__ b_f, const float* __restrict__ b_r,
    const float* __restrict__ b_cx,
    unsigned short* __restrict__ projc) {
  __shared__ __align__(16) unsigned short smem[17408];  // 34.8 KB
  unsigned short* As0 = smem;          // 4096 shorts each
  unsigned short* As1 = smem + 4096;
  unsigned short* Bs0 = smem + 8192;
  unsigned short* Bs1 = smem + 12288;

  int tid  = threadIdx.x;
  int wave = tid >> 6;
  int lane = tid & 63;
  int quad = lane >> 4;
  int l16  = lane & 15;
  int m0 = blockIdx.y * BM;
  int n0 = blockIdx.x * BN;
  int wm = (wave >> 1) * 64;
  int wn = (wave & 1) * 64;

  int row0 = tid >> 2;
  int cl0  = (tid & 3) ^ ((row0 >> 1) & 3);
  int row1 = 64 + row0;
  int cl1  = (tid & 3) ^ ((row1 >> 1) & 3);

  float4v acc[4][4] = {};

#define STAGE(Adst, Bdst, kt) do { \
    gld16(ebfc + (size_t)(m0 + row0) * K_DIM + (kt) + cl0 * 8, (Adst) + tid * 8); \
    gld16(wcat + (size_t)(n0 + row0) * K_DIM + (kt) + cl0 * 8, (Bdst) + tid * 8); \
    gld16(ebfc + (size_t)(m0 + row1) * K_DIM + (kt) + cl1 * 8, (Adst) + 2048 + tid * 8); \
    gld16(wcat + (size_t)(n0 + row1) * K_DIM + (kt) + cl1 * 8, (Bdst) + 2048 + tid * 8); } while (0)

  STAGE(As0, Bs0, 0);
  __syncthreads();

  for (int ki = 0; ki < K_DIM / BK; ki++) {
    unsigned short* Ac = (ki & 1) ? As1 : As0;
    unsigned short* Bc = (ki & 1) ? Bs1 : Bs0;
    if (ki + 1 < K_DIM / BK) {
      unsigned short* An = (ki & 1) ? As0 : As1;
      unsigned short* Bn = (ki & 1) ? Bs0 : Bs1;
      STAGE(An, Bn, (ki + 1) * BK);
    }
    short8 af[4], bfr[4];
#pragma unroll
    for (int i = 0; i < 4; i++) {
      int r = wm + i * 16 + l16;
      int p = quad ^ ((r >> 1) & 3);
      af[i] = *(const short8*)(Ac + r * BK + p * 8);
    }
#pragma unroll
    for (int j = 0; j < 4; j++) {
      int r = wn + j * 16 + l16;
      int p = quad ^ ((r >> 1) & 3);
      bfr[j] = *(const short8*)(Bc + r * BK + p * 8);
    }
#pragma unroll
    for (int i = 0; i < 4; i++)
#pragma unroll
      for (int j = 0; j < 4; j++)
        acc[i][j] = __builtin_amdgcn_mfma_f32_16x16x32_bf16(af[i], bfr[j], acc[i][j], 0, 0, 0);
    __syncthreads();
  }

  // ---- epilogue: bias/sigmoid, then LDS transpose -> coalesced stores ----
  int mat = n0 / H_DIM;
  const float* bias = (mat == 1) ? b_f : (mat == 2) ? b_r : b_cx;
#pragma unroll
  for (int i = 0; i < 4; i++) {
    int row = wm + i * 16 + quad * 4;
#pragma unroll
    for (int j = 0; j < 4; j++) {
      int col = wn + j * 16 + l16;
      int h = n0 + col - mat * H_DIM;
      float bv = (mat == 0) ? 0.0f : bias[h];
#pragma unroll
      for (int r = 0; r < 4; r++) {
        float v = acc[i][j][r] + bv;
        if (mat == 1 || mat == 2) v = sigmoid_f(v);
        smem[(row + r) * 136 + col] = f2bf(v);
      }
    }
  }
  __syncthreads();
  size_t matBase = (size_t)mat * MC * H_DIM;
  int hb = n0 - mat * H_DIM;
#pragma unroll
  for (int s = 0; s < 8; s++) {
    int idx = s * 256 + tid;
    int row = idx >> 4;
    int col8 = (idx & 15) * 8;
    short8 v = *(const short8*)(smem + row * 136 + col8);
    *(short8*)(projc + matBase + (size_t)(m0 + row) * H_DIM + hb + col8) = v;
  }
}

// ---------------------------------------------------------------------------
// Kernel 4a (scan1): per-segment summaries P = prod f, Q = c_out given c_in=0.
// thread <-> (seg, b, 2 h's). 1536 blocks x 128 threads.
// ---------------------------------------------------------------------------
__global__ __launch_bounds__(128) void scan1_kernel(
    const unsigned short* __restrict__ projc,
    float* __restrict__ Pw, float* __restrict__ Qw) {
  int blk = blockIdx.x;
  int seg = blk / (B_DIM * 3);
  int rem = blk % (B_DIM * 3);
  int b = rem / 3, hc = rem % 3;
  int h = hc * 256 + threadIdx.x * 2;
  const size_t mstr = (size_t)MC * H_DIM;
  size_t idx0 = ((size_t)(seg * L_SEG) * B_DIM + b) * H_DIM + h;
  float p0 = 1.f, p1 = 1.f, c0 = 0.f, c1 = 0.f;
#pragma unroll 4
  for (int t = 0; t < L_SEG; t++) {
    size_t id = idx0 + (size_t)t * BH;
    ushort2 xp = *(const ushort2*)(projc + id);
    ushort2 ff = *(const ushort2*)(projc + mstr + id);
    float f0 = bf2f(ff.x), f1 = bf2f(ff.y);
    float x0 = bf2f(xp.x), x1 = bf2f(xp.y);
    c0 = fmaf(f0, c0 - x0, x0);
    c1 = fmaf(f1, c1 - x1, x1);
    p0 *= f0; p1 *= f1;
  }
  int o = seg * BH + b * H_DIM + h;
  *(float2*)(Pw + o) = make_float2(p0, p1);
  *(float2*)(Qw + o) = make_float2(c0, c1);
}

// ---------------------------------------------------------------------------
// Kernel 4b (prefix): chain segments exactly: c_out = P*c_in + Q.
// Also folds previous chunk's segmax into hm_state. 96 blocks x 256.
// ---------------------------------------------------------------------------
__global__ __launch_bounds__(256) void prefix_kernel(
    const float* __restrict__ Pw, const float* __restrict__ Qw,
    float* __restrict__ cin, float* __restrict__ c_state,
    const float* __restrict__ segmax, float* __restrict__ hm_state,
    int first, int hm_init) {
  int gid = blockIdx.x * 256 + threadIdx.x;
  float c = first ? 0.f : c_state[gid];
#pragma unroll
  for (int s = 0; s < S_SEG; s++) {
    cin[s * BH + gid] = c;
    c = fmaf(Pw[s * BH + gid], c, Qw[s * BH + gid]);
  }
  c_state[gid] = c;
  if (!first) {
    float m = segmax[gid];
#pragma unroll
    for (int s = 1; s < S_SEG; s++) m = fmaxf(m, segmax[s * BH + gid]);
    hm_state[gid] = hm_init ? m : fmaxf(hm_state[gid], m);
  }
}

// ---------------------------------------------------------------------------
// Kernel 4c (scan2): replay each segment from true c_in; h + segment max.
// ---------------------------------------------------------------------------
__global__ __launch_bounds__(128) void scan2_kernel(
    const unsigned short* __restrict__ projc,
    const float* __restrict__ cin, float* __restrict__ segmax) {
  int blk = blockIdx.x;
  int seg = blk / (B_DIM * 3);
  int rem = blk % (B_DIM * 3);
  int b = rem / 3, hc = rem % 3;
  int h = hc * 256 + threadIdx.x * 2;
  const size_t mstr = (size_t)MC * H_DIM;
  size_t idx0 = ((size_t)(seg * L_SEG) * B_DIM + b) * H_DIM + h;
  int o = seg * BH + b * H_DIM + h;
  float2 cv = *(const float2*)(cin + o);
  float c0 = cv.x, c1 = cv.y, m0 = -1e30f, m1 = -1e30f;
#pragma unroll 4
  for (int t = 0; t < L_SEG; t++) {
    size_t id = idx0 + (size_t)t * BH;
    ushort2 xp = *(const ushort2*)(projc + id);
    ushort2 ff = *(const ushort2*)(projc + mstr + id);
    ushort2 rr = *(const ushort2*)(projc + 2 * mstr + id);
    ushort2 cx = *(const ushort2*)(projc + 3 * mstr + id);
    float f0 = bf2f(ff.x), f1 = bf2f(ff.y);
    float x0 = bf2f(xp.x), x1 = bf2f(xp.y);
    float r0 = bf2f(rr.x), r1 = bf2f(rr.y);
    float g0 = bf2f(cx.x), g1 = bf2f(cx.y);
    c0 = fmaf(f0, c0 - x0, x0);
    c1 = fmaf(f1, c1 - x1, x1);
    float h0 = fmaf(r0, tanh_f(c0) - g0, g0);
    float h1 = fmaf(r1, tanh_f(c1) - g1, g1);
    m0 = fmaxf(m0, h0); m1 = fmaxf(m1, h1);
  }
  *(float2*)(segmax + o) = make_float2(m0, m1);
}

// ---------------------------------------------------------------------------
// Kernel 4d: final pool = tanh(tanh(max(hm_state, last chunk's segmax)))
// ---------------------------------------------------------------------------
__global__ __launch_bounds__(256) void pool_final_kernel(
    const float* __restrict__ segmax, const float* __restrict__ hm_state,
    float* __restrict__ pooled) {
  int gid = blockIdx.x * 256 + threadIdx.x;
  float m = hm_state[gid];
#pragma unroll
  for (int s = 0; s < S_SEG; s++) m = fmaxf(m, segmax[s * BH + gid]);
  pooled[gid] = tanh_f(tanh_f(m));
}

// ---------------------------------------------------------------------------
// Kernel 5: classifier  logit[b][c] = pooled[b]·W_out[c] + b_out[c]
// ---------------------------------------------------------------------------
__global__ __launch_bounds__(64) void classifier_kernel(
    const float* __restrict__ pooled, const float* __restrict__ W_out,
    const float* __restrict__ b_out, float* __restrict__ out) {
  int b = blockIdx.x / C_DIM;
  int c = blockIdx.x % C_DIM;
  int lane = threadIdx.x;
  float s = 0.0f;
#pragma unroll
  for (int i = 0; i < H_DIM / 64; i++) {
    int h = i * 64 + lane;
    s += pooled[(size_t)b * H_DIM + h] * W_out[(size_t)c * H_DIM + h];
  }
#pragma unroll
  for (int off = 32; off; off >>= 1) s += __shfl_down(s, off, 64);
  if (lane == 0) out[b * C_DIM + c] = s + b_out[c];
}

// ---------------------------------------------------------------------------
extern "C" void kernel_launch(void* const* d_in, const int* in_sizes, int n_in,
                              void* d_out, int out_size, void* d_ws, size_t ws_size,
                              hipStream_t stream) {
  const int*   x     = (const int*)d_in[0];
  const float* table = (const float*)d_in[1];
  const float* W_x   = (const float*)d_in[2];
  const float* W_f   = (const float*)d_in[3];
  const float* b_f   = (const float*)d_in[4];
  const float* W_r   = (const float*)d_in[5];
  const float* b_r   = (const float*)d_in[6];
  const float* W_cx  = (const float*)d_in[7];
  const float* b_cx  = (const float*)d_in[8];
  const float* W_out = (const float*)d_in[9];
  const float* b_out = (const float*)d_in[10];

  // workspace layout (~245 MB; ws_size ~411 MB per harness fill size)
  char* ws = (char*)d_ws;
  size_t off = 0;
  unsigned short* wcat  = (unsigned short*)(ws + off); off += (size_t)N_DIM * K_DIM * 2;
  unsigned short* ebfc  = (unsigned short*)(ws + off); off += (size_t)MC * K_DIM * 2;
  unsigned short* projc = (unsigned short*)(ws + off); off += (size_t)4 * MC * H_DIM * 2;
  float* Pw     = (float*)(ws + off); off += (size_t)S_SEG * BH * 4;
  float* Qw     = (float*)(ws + off); off += (size_t)S_SEG * BH * 4;
  float* cin    = (float*)(ws + off); off += (size_t)S_SEG * BH * 4;
  float* segmax = (float*)(ws + off); off += (size_t)S_SEG * BH * 4;
  float* c_st   = (float*)(ws + off); off += (size_t)BH * 4;
  float* hm_st  = (float*)(ws + off); off += (size_t)BH * 4;
  float* pooled = (float*)(ws + off); off += (size_t)BH * 4;

  convert_w_kernel<<<(N_DIM * K_DIM / 4) / 256, 256, 0, stream>>>(W_x, W_f, W_r, W_cx, wcat);

  dim3 g(N_DIM / BN, MC / BM);   // (24, 256)
  for (int ch = 0; ch < NCHUNK; ch++) {
    gather_embed_kernel<<<(MC * K_DIM / 4) / 256, 256, 0, stream>>>(x + (size_t)ch * MC, table, ebfc);
    gemm_kernel<<<g, 256, 0, stream>>>(ebfc, wcat, b_f, b_r, b_cx, projc);
    scan1_kernel<<<S_SEG * B_DIM * 3, 128, 0, stream>>>(projc, Pw, Qw);
    prefix_kernel<<<BH / 256, 256, 0, stream>>>(Pw, Qw, cin, c_st, segmax, hm_st,
                                                ch == 0, ch == 1);
    scan2_kernel<<<S_SEG * B_DIM * 3, 128, 0, stream>>>(projc, cin, segmax);
  }
  pool_final_kernel<<<BH / 256, 256, 0, stream>>>(segmax, hm_st, pooled);
  classifier_kernel<<<B_DIM * C_DIM, 64, 0, stream>>>(pooled, W_out, b_out, (float*)d_out);
}